// Round 1
// baseline (937.149 us; speedup 1.0000x reference)
//
#include <hip/hip_runtime.h>

#define HID 128

// ---------------------------------------------------------------- utilities
#define ELT(v, u) ((u) == 0 ? (v).x : (u) == 1 ? (v).y : (u) == 2 ? (v).z : (v).w)

// ---------------------------------------------------------------- init: zero count + mean accumulator
__global__ __launch_bounds__(256) void k_init(int* __restrict__ cnt,
                                              float* __restrict__ outmean, int n) {
  int i = blockIdx.x * 256 + threadIdx.x;
  if (i < n) cnt[i] = 0;
  if (i < HID) outmean[i] = 0.f;
}

// ---------------------------------------------------------------- embed: h0 = relu([z,pos] @ W_in + b_in)
__global__ __launch_bounds__(256) void k_embed(const float* __restrict__ pos,
                                               const int* __restrict__ an,
                                               const float* __restrict__ Win,
                                               const float* __restrict__ bin,
                                               float* __restrict__ h, int n) {
  int t = blockIdx.x * 256 + threadIdx.x;
  int i = t >> 5, cg = t & 31;
  if (i >= n) return;
  int j0 = cg << 2;
  float z  = (float)an[i] / 10.0f;
  float px = pos[3 * i + 0], py = pos[3 * i + 1], pz = pos[3 * i + 2];
  float4 w0 = *(const float4*)&Win[0 * HID + j0];
  float4 w1 = *(const float4*)&Win[1 * HID + j0];
  float4 w2 = *(const float4*)&Win[2 * HID + j0];
  float4 w3 = *(const float4*)&Win[3 * HID + j0];
  float4 b  = *(const float4*)&bin[j0];
  float4 o;
  o.x = fmaxf(fmaf(z, w0.x, fmaf(px, w1.x, fmaf(py, w2.x, fmaf(pz, w3.x, b.x)))), 0.f);
  o.y = fmaxf(fmaf(z, w0.y, fmaf(px, w1.y, fmaf(py, w2.y, fmaf(pz, w3.y, b.y)))), 0.f);
  o.z = fmaxf(fmaf(z, w0.z, fmaf(px, w1.z, fmaf(py, w2.z, fmaf(pz, w3.z, b.z)))), 0.f);
  o.w = fmaxf(fmaf(z, w0.w, fmaf(px, w1.w, fmaf(py, w2.w, fmaf(pz, w3.w, b.w)))), 0.f);
  *(float4*)&h[(size_t)i * HID + j0] = o;
}

// ---------------------------------------------------------------- CSR build
__global__ __launch_bounds__(256) void k_count(const int* __restrict__ dst,
                                               int* __restrict__ cnt, int e) {
  int i = blockIdx.x * 256 + threadIdx.x;
  if (i < e) atomicAdd(&cnt[dst[i]], 1);
}

__global__ __launch_bounds__(1024) void k_scan(const int* __restrict__ cnt,
                                               int* __restrict__ offs,
                                               int* __restrict__ cursor, int n) {
  __shared__ int part[1024];
  int t = threadIdx.x;
  int chunk = (n + 1023) / 1024;
  int beg = t * chunk;
  int end = beg + chunk; if (end > n) end = n;
  int s = 0;
  for (int i = beg; i < end; ++i) s += cnt[i];
  part[t] = s;
  __syncthreads();
  for (int d = 1; d < 1024; d <<= 1) {
    int v = 0;
    if (t >= d) v = part[t - d];
    __syncthreads();
    if (t >= d) part[t] += v;
    __syncthreads();
  }
  int base = (t == 0) ? 0 : part[t - 1];
  for (int i = beg; i < end; ++i) {
    offs[i] = base; cursor[i] = base;
    base += cnt[i];
  }
  if (t == 1023) offs[n] = part[1023];
}

__global__ __launch_bounds__(256) void k_fill(const int* __restrict__ src,
                                              const int* __restrict__ dst,
                                              int* __restrict__ cursor,
                                              int* __restrict__ csr, int e) {
  int i = blockIdx.x * 256 + threadIdx.x;
  if (i < e) {
    int p = atomicAdd(&cursor[dst[i]], 1);
    csr[p] = src[i];
  }
}

// ---------------------------------------------------------------- mean aggregation: one wave per node
__global__ __launch_bounds__(256) void k_aggmean(const float* __restrict__ h,
                                                 const int* __restrict__ csr,
                                                 const int* __restrict__ offs,
                                                 float* __restrict__ out, int n) {
  int w = (blockIdx.x * 256 + threadIdx.x) >> 6;
  int lane = threadIdx.x & 63;
  if (w >= n) return;
  int beg = offs[w], end = offs[w + 1];
  float ax = 0.f, ay = 0.f;
  int e = beg;
  for (; e + 4 <= end; e += 4) {
    int s0 = csr[e + 0], s1 = csr[e + 1], s2 = csr[e + 2], s3 = csr[e + 3];
    float2 v0 = *(const float2*)&h[(size_t)s0 * HID + lane * 2];
    float2 v1 = *(const float2*)&h[(size_t)s1 * HID + lane * 2];
    float2 v2 = *(const float2*)&h[(size_t)s2 * HID + lane * 2];
    float2 v3 = *(const float2*)&h[(size_t)s3 * HID + lane * 2];
    ax += (v0.x + v1.x) + (v2.x + v3.x);
    ay += (v0.y + v1.y) + (v2.y + v3.y);
  }
  for (; e < end; ++e) {
    int s0 = csr[e];
    float2 v0 = *(const float2*)&h[(size_t)s0 * HID + lane * 2];
    ax += v0.x; ay += v0.y;
  }
  int c = end - beg;
  float inv = (c > 0) ? 1.0f / (float)c : 0.0f;
  float2 o; o.x = ax * inv; o.y = ay * inv;
  *(float2*)&out[(size_t)w * HID + lane * 2] = o;
}

// ---------------------------------------------------------------- fused SAGE GEMM: out = act(ha@Wl + hs@Wr + b)
// block: 256 threads, 32-row tile; thread computes 4 rows x 4 cols.
__global__ __launch_bounds__(256) void k_sage(const float* __restrict__ ha,
                                              const float* __restrict__ hs,
                                              const float* __restrict__ Wl,
                                              const float* __restrict__ Wr,
                                              const float* __restrict__ bias,
                                              float* __restrict__ out, int n,
                                              int do_relu) {
  __shared__ float sWl[32][HID];
  __shared__ float sWr[32][HID];
  __shared__ float sA[32][32];
  __shared__ float sH[32][32];
  int tid = threadIdx.x;
  int cg = tid & 31, rg = tid >> 5;
  int j0 = cg << 2, r0 = rg << 2;
  int row0 = blockIdx.x << 5;
  float4 acc[4];
#pragma unroll
  for (int rr = 0; rr < 4; ++rr) acc[rr] = make_float4(0.f, 0.f, 0.f, 0.f);

  for (int kc = 0; kc < HID; kc += 32) {
    __syncthreads();
#pragma unroll
    for (int i = 0; i < 4; ++i) {
      int f = tid + (i << 8);
      int wr_ = f >> 5, wc = (f & 31) << 2;
      *(float4*)&sWl[wr_][wc] = *(const float4*)&Wl[(kc + wr_) * HID + wc];
      *(float4*)&sWr[wr_][wc] = *(const float4*)&Wr[(kc + wr_) * HID + wc];
    }
    {
      int rr_ = tid >> 3, kk = (tid & 7) << 2;
      int row = row0 + rr_;
      float4 va = make_float4(0.f, 0.f, 0.f, 0.f), vh = va;
      if (row < n) {
        size_t g = (size_t)row * HID + kc + kk;
        va = *(const float4*)&ha[g];
        vh = *(const float4*)&hs[g];
      }
      *(float4*)&sA[rr_][kk] = va;
      *(float4*)&sH[rr_][kk] = vh;
    }
    __syncthreads();
#pragma unroll
    for (int k = 0; k < 32; k += 4) {
      float4 A_[4], H_[4];
#pragma unroll
      for (int rr = 0; rr < 4; ++rr) {
        A_[rr] = *(const float4*)&sA[r0 + rr][k];
        H_[rr] = *(const float4*)&sH[r0 + rr][k];
      }
#pragma unroll
      for (int u = 0; u < 4; ++u) {
        float4 wl = *(const float4*)&sWl[k + u][j0];
        float4 wr2 = *(const float4*)&sWr[k + u][j0];
#pragma unroll
        for (int rr = 0; rr < 4; ++rr) {
          float av = ELT(A_[rr], u), hv = ELT(H_[rr], u);
          acc[rr].x = fmaf(av, wl.x, fmaf(hv, wr2.x, acc[rr].x));
          acc[rr].y = fmaf(av, wl.y, fmaf(hv, wr2.y, acc[rr].y));
          acc[rr].z = fmaf(av, wl.z, fmaf(hv, wr2.z, acc[rr].z));
          acc[rr].w = fmaf(av, wl.w, fmaf(hv, wr2.w, acc[rr].w));
        }
      }
    }
  }
  float4 b4 = *(const float4*)&bias[j0];
#pragma unroll
  for (int rr = 0; rr < 4; ++rr) {
    int row = row0 + r0 + rr;
    if (row < n) {
      float4 o = acc[rr];
      o.x += b4.x; o.y += b4.y; o.z += b4.z; o.w += b4.w;
      if (do_relu) {
        o.x = fmaxf(o.x, 0.f); o.y = fmaxf(o.y, 0.f);
        o.z = fmaxf(o.z, 0.f); o.w = fmaxf(o.w, 0.f);
      }
      *(float4*)&out[(size_t)row * HID + j0] = o;
    }
  }
}

// ---------------------------------------------------------------- single GEMM: out = h@W + b (no relu)
__global__ __launch_bounds__(256) void k_single(const float* __restrict__ hs,
                                                const float* __restrict__ W,
                                                const float* __restrict__ bias,
                                                float* __restrict__ out, int n) {
  __shared__ float sW[32][HID];
  __shared__ float sH[32][32];
  int tid = threadIdx.x;
  int cg = tid & 31, rg = tid >> 5;
  int j0 = cg << 2, r0 = rg << 2;
  int row0 = blockIdx.x << 5;
  float4 acc[4];
#pragma unroll
  for (int rr = 0; rr < 4; ++rr) acc[rr] = make_float4(0.f, 0.f, 0.f, 0.f);

  for (int kc = 0; kc < HID; kc += 32) {
    __syncthreads();
#pragma unroll
    for (int i = 0; i < 4; ++i) {
      int f = tid + (i << 8);
      int wr_ = f >> 5, wc = (f & 31) << 2;
      *(float4*)&sW[wr_][wc] = *(const float4*)&W[(kc + wr_) * HID + wc];
    }
    {
      int rr_ = tid >> 3, kk = (tid & 7) << 2;
      int row = row0 + rr_;
      float4 vh = make_float4(0.f, 0.f, 0.f, 0.f);
      if (row < n) vh = *(const float4*)&hs[(size_t)row * HID + kc + kk];
      *(float4*)&sH[rr_][kk] = vh;
    }
    __syncthreads();
#pragma unroll
    for (int k = 0; k < 32; k += 4) {
      float4 H_[4];
#pragma unroll
      for (int rr = 0; rr < 4; ++rr) H_[rr] = *(const float4*)&sH[r0 + rr][k];
#pragma unroll
      for (int u = 0; u < 4; ++u) {
        float4 w = *(const float4*)&sW[k + u][j0];
#pragma unroll
        for (int rr = 0; rr < 4; ++rr) {
          float hv = ELT(H_[rr], u);
          acc[rr].x = fmaf(hv, w.x, acc[rr].x);
          acc[rr].y = fmaf(hv, w.y, acc[rr].y);
          acc[rr].z = fmaf(hv, w.z, acc[rr].z);
          acc[rr].w = fmaf(hv, w.w, acc[rr].w);
        }
      }
    }
  }
  float4 b4 = *(const float4*)&bias[j0];
#pragma unroll
  for (int rr = 0; rr < 4; ++rr) {
    int row = row0 + r0 + rr;
    if (row < n) {
      float4 o = acc[rr];
      o.x += b4.x; o.y += b4.y; o.z += b4.z; o.w += b4.w;
      *(float4*)&out[(size_t)row * HID + j0] = o;
    }
  }
}

// ---------------------------------------------------------------- column mean: outmean[j] += sum_block(ns[:,j]) / N
__global__ __launch_bounds__(256) void k_colmean(const float* __restrict__ ns,
                                                 float* __restrict__ outmean,
                                                 int n, float inv) {
  __shared__ float red[256];
  int t = threadIdx.x;
  int col = t & 127, rp = t >> 7;
  int row0 = blockIdx.x * 256;
  float s = 0.f;
  for (int rr = rp; rr < 256; rr += 2) {
    int row = row0 + rr;
    if (row < n) s += ns[(size_t)row * HID + col];
  }
  red[t] = s;
  __syncthreads();
  if (t < 128) atomicAdd(&outmean[col], (red[t] + red[t + 128]) * inv);
}

// ---------------------------------------------------------------- launch
extern "C" void kernel_launch(void* const* d_in, const int* in_sizes, int n_in,
                              void* d_out, int out_size, void* d_ws, size_t ws_size,
                              hipStream_t stream) {
  const float* pos  = (const float*)d_in[0];
  const int*   an   = (const int*)d_in[1];
  const int*   ei   = (const int*)d_in[2];
  const float* Win  = (const float*)d_in[3];
  const float* bin  = (const float*)d_in[4];
  const float* W1l  = (const float*)d_in[5];
  const float* b1   = (const float*)d_in[6];
  const float* W1r  = (const float*)d_in[7];
  const float* W2l  = (const float*)d_in[8];
  const float* b2   = (const float*)d_in[9];
  const float* W2r  = (const float*)d_in[10];
  const float* Wout = (const float*)d_in[11];
  const float* bout = (const float*)d_in[12];

  int N = in_sizes[0] / 3;
  int E = in_sizes[2] / 2;
  const int* srcl = ei;
  const int* dstl = ei + E;

  float* outmean = (float*)d_out;
  float* ns      = (float*)d_out + HID;

  char* p = (char*)d_ws;
  auto take = [&](size_t bytes) {
    char* q = p;
    p += (bytes + 255) & ~(size_t)255;
    return q;
  };
  float* A      = (float*)take((size_t)N * HID * 4);
  float* B      = (float*)take((size_t)N * HID * 4);
  float* D      = (float*)take((size_t)N * HID * 4);
  int*   cnt    = (int*)take((size_t)N * 4);
  int*   offs   = (int*)take((size_t)(N + 1) * 4);
  int*   cursor = (int*)take((size_t)N * 4);
  int*   csr    = (int*)take((size_t)E * 4);

  int gN256   = (N + 255) / 256;
  int gE256   = (E + 255) / 256;
  int gEmbed  = (int)(((size_t)N * 32 + 255) / 256);
  int gTile32 = (N + 31) / 32;
  int gWave   = (N + 3) / 4;

  k_init<<<gN256, 256, 0, stream>>>(cnt, outmean, N);
  k_embed<<<gEmbed, 256, 0, stream>>>(pos, an, Win, bin, A, N);
  k_count<<<gE256, 256, 0, stream>>>(dstl, cnt, E);
  k_scan<<<1, 1024, 0, stream>>>(cnt, offs, cursor, N);
  k_fill<<<gE256, 256, 0, stream>>>(srcl, dstl, cursor, csr, E);

  // conv1
  k_aggmean<<<gWave, 256, 0, stream>>>(A, csr, offs, D, N);
  k_sage<<<gTile32, 256, 0, stream>>>(D, A, W1l, W1r, b1, B, N, 1);
  // conv2
  k_aggmean<<<gWave, 256, 0, stream>>>(B, csr, offs, D, N);
  k_sage<<<gTile32, 256, 0, stream>>>(D, B, W2l, W2r, b2, A, N, 1);
  // output projection
  k_single<<<gTile32, 256, 0, stream>>>(A, Wout, bout, ns, N);
  k_colmean<<<gN256, 256, 0, stream>>>(ns, outmean, N, 1.0f / (float)N);
}

// Round 2
// 727.568 us; speedup vs baseline: 1.2881x; 1.2881x over previous
//
#include <hip/hip_runtime.h>

#define HID 128
#define SCAN_CHUNK 2048

// ---------------------------------------------------------------- utilities
#define ELT(v, u) ((u) == 0 ? (v).x : (u) == 1 ? (v).y : (u) == 2 ? (v).z : (v).w)

// ---------------------------------------------------------------- init: zero count + mean accumulator
__global__ __launch_bounds__(256) void k_init(int* __restrict__ cnt,
                                              float* __restrict__ outmean, int n) {
  int i = blockIdx.x * 256 + threadIdx.x;
  if (i < n) cnt[i] = 0;
  if (i < HID) outmean[i] = 0.f;
}

// ---------------------------------------------------------------- embed: h0 = relu([z,pos] @ W_in + b_in)
__global__ __launch_bounds__(256) void k_embed(const float* __restrict__ pos,
                                               const int* __restrict__ an,
                                               const float* __restrict__ Win,
                                               const float* __restrict__ bin,
                                               float* __restrict__ h, int n) {
  int t = blockIdx.x * 256 + threadIdx.x;
  int i = t >> 5, cg = t & 31;
  if (i >= n) return;
  int j0 = cg << 2;
  float z  = (float)an[i] / 10.0f;
  float px = pos[3 * i + 0], py = pos[3 * i + 1], pz = pos[3 * i + 2];
  float4 w0 = *(const float4*)&Win[0 * HID + j0];
  float4 w1 = *(const float4*)&Win[1 * HID + j0];
  float4 w2 = *(const float4*)&Win[2 * HID + j0];
  float4 w3 = *(const float4*)&Win[3 * HID + j0];
  float4 b  = *(const float4*)&bin[j0];
  float4 o;
  o.x = fmaxf(fmaf(z, w0.x, fmaf(px, w1.x, fmaf(py, w2.x, fmaf(pz, w3.x, b.x)))), 0.f);
  o.y = fmaxf(fmaf(z, w0.y, fmaf(px, w1.y, fmaf(py, w2.y, fmaf(pz, w3.y, b.y)))), 0.f);
  o.z = fmaxf(fmaf(z, w0.z, fmaf(px, w1.z, fmaf(py, w2.z, fmaf(pz, w3.z, b.z)))), 0.f);
  o.w = fmaxf(fmaf(z, w0.w, fmaf(px, w1.w, fmaf(py, w2.w, fmaf(pz, w3.w, b.w)))), 0.f);
  *(float4*)&h[(size_t)i * HID + j0] = o;
}

// ---------------------------------------------------------------- CSR build
__global__ __launch_bounds__(256) void k_count(const int* __restrict__ dst,
                                               int* __restrict__ cnt, int e) {
  int i = blockIdx.x * 256 + threadIdx.x;
  if (i < e) atomicAdd(&cnt[dst[i]], 1);
}

// stage 1: per-block sums of 2048 counts
__global__ __launch_bounds__(256) void k_scan_blocksum(const int* __restrict__ cnt,
                                                       int* __restrict__ partial, int n) {
  __shared__ int red[256];
  int t = threadIdx.x;
  int base = blockIdx.x * SCAN_CHUNK + t * 8;
  int s = 0;
#pragma unroll
  for (int i = 0; i < 8; ++i) {
    int idx = base + i;
    if (idx < n) s += cnt[idx];
  }
  red[t] = s;
  __syncthreads();
  for (int d = 128; d > 0; d >>= 1) {
    if (t < d) red[t] += red[t + d];
    __syncthreads();
  }
  if (t == 0) partial[blockIdx.x] = red[0];
}

// stage 2: exclusive scan of block partials (nb <= 256)
__global__ __launch_bounds__(256) void k_scan_partials(int* __restrict__ partial, int nb) {
  __shared__ int buf[256];
  int t = threadIdx.x;
  int v = (t < nb) ? partial[t] : 0;
  buf[t] = v;
  __syncthreads();
  for (int d = 1; d < 256; d <<= 1) {
    int u = (t >= d) ? buf[t - d] : 0;
    __syncthreads();
    buf[t] += u;
    __syncthreads();
  }
  if (t < nb) partial[t] = buf[t] - v;  // exclusive
}

// stage 3: local scan + base -> offs, cursor
__global__ __launch_bounds__(256) void k_scan_write(const int* __restrict__ cnt,
                                                    const int* __restrict__ partial,
                                                    int* __restrict__ offs,
                                                    int* __restrict__ cursor,
                                                    int n, int e) {
  __shared__ int red[256];
  int t = threadIdx.x;
  int blk = blockIdx.x;
  int base = blk * SCAN_CHUNK + t * 8;
  int c[8];
  int s = 0;
#pragma unroll
  for (int i = 0; i < 8; ++i) {
    int idx = base + i;
    c[i] = (idx < n) ? cnt[idx] : 0;
    s += c[i];
  }
  red[t] = s;
  __syncthreads();
  for (int d = 1; d < 256; d <<= 1) {
    int u = (t >= d) ? red[t - d] : 0;
    __syncthreads();
    red[t] += u;
    __syncthreads();
  }
  int run = partial[blk] + ((t > 0) ? red[t - 1] : 0);
#pragma unroll
  for (int i = 0; i < 8; ++i) {
    int idx = base + i;
    if (idx < n) {
      offs[idx] = run;
      cursor[idx] = run;
      run += c[i];
    }
  }
  if (blk == 0 && t == 0) offs[n] = e;
}

__global__ __launch_bounds__(256) void k_fill(const int* __restrict__ src,
                                              const int* __restrict__ dst,
                                              int* __restrict__ cursor,
                                              int* __restrict__ csr, int e) {
  int i = blockIdx.x * 256 + threadIdx.x;
  if (i < e) {
    int p = atomicAdd(&cursor[dst[i]], 1);
    csr[p] = src[i];
  }
}

// ---------------------------------------------------------------- mean aggregation: one wave per node
__global__ __launch_bounds__(256) void k_aggmean(const float* __restrict__ h,
                                                 const int* __restrict__ csr,
                                                 const int* __restrict__ offs,
                                                 float* __restrict__ out, int n) {
  int w = (blockIdx.x * 256 + threadIdx.x) >> 6;
  int lane = threadIdx.x & 63;
  if (w >= n) return;
  int beg = offs[w], end = offs[w + 1];
  float ax = 0.f, ay = 0.f;
  int e = beg;
  for (; e + 4 <= end; e += 4) {
    int s0 = csr[e + 0], s1 = csr[e + 1], s2 = csr[e + 2], s3 = csr[e + 3];
    float2 v0 = *(const float2*)&h[(size_t)s0 * HID + lane * 2];
    float2 v1 = *(const float2*)&h[(size_t)s1 * HID + lane * 2];
    float2 v2 = *(const float2*)&h[(size_t)s2 * HID + lane * 2];
    float2 v3 = *(const float2*)&h[(size_t)s3 * HID + lane * 2];
    ax += (v0.x + v1.x) + (v2.x + v3.x);
    ay += (v0.y + v1.y) + (v2.y + v3.y);
  }
  for (; e < end; ++e) {
    int s0 = csr[e];
    float2 v0 = *(const float2*)&h[(size_t)s0 * HID + lane * 2];
    ax += v0.x; ay += v0.y;
  }
  int c = end - beg;
  float inv = (c > 0) ? 1.0f / (float)c : 0.0f;
  float2 o; o.x = ax * inv; o.y = ay * inv;
  *(float2*)&out[(size_t)w * HID + lane * 2] = o;
}

// ---------------------------------------------------------------- fused SAGE GEMM: out = act(ha@Wl + hs@Wr + b)
__global__ __launch_bounds__(256) void k_sage(const float* __restrict__ ha,
                                              const float* __restrict__ hs,
                                              const float* __restrict__ Wl,
                                              const float* __restrict__ Wr,
                                              const float* __restrict__ bias,
                                              float* __restrict__ out, int n,
                                              int do_relu) {
  __shared__ float sWl[32][HID];
  __shared__ float sWr[32][HID];
  __shared__ float sA[32][32];
  __shared__ float sH[32][32];
  int tid = threadIdx.x;
  int cg = tid & 31, rg = tid >> 5;
  int j0 = cg << 2, r0 = rg << 2;
  int row0 = blockIdx.x << 5;
  float4 acc[4];
#pragma unroll
  for (int rr = 0; rr < 4; ++rr) acc[rr] = make_float4(0.f, 0.f, 0.f, 0.f);

  for (int kc = 0; kc < HID; kc += 32) {
    __syncthreads();
#pragma unroll
    for (int i = 0; i < 4; ++i) {
      int f = tid + (i << 8);
      int wr_ = f >> 5, wc = (f & 31) << 2;
      *(float4*)&sWl[wr_][wc] = *(const float4*)&Wl[(kc + wr_) * HID + wc];
      *(float4*)&sWr[wr_][wc] = *(const float4*)&Wr[(kc + wr_) * HID + wc];
    }
    {
      int rr_ = tid >> 3, kk = (tid & 7) << 2;
      int row = row0 + rr_;
      float4 va = make_float4(0.f, 0.f, 0.f, 0.f), vh = va;
      if (row < n) {
        size_t g = (size_t)row * HID + kc + kk;
        va = *(const float4*)&ha[g];
        vh = *(const float4*)&hs[g];
      }
      *(float4*)&sA[rr_][kk] = va;
      *(float4*)&sH[rr_][kk] = vh;
    }
    __syncthreads();
#pragma unroll
    for (int k = 0; k < 32; k += 4) {
      float4 A_[4], H_[4];
#pragma unroll
      for (int rr = 0; rr < 4; ++rr) {
        A_[rr] = *(const float4*)&sA[r0 + rr][k];
        H_[rr] = *(const float4*)&sH[r0 + rr][k];
      }
#pragma unroll
      for (int u = 0; u < 4; ++u) {
        float4 wl = *(const float4*)&sWl[k + u][j0];
        float4 wr2 = *(const float4*)&sWr[k + u][j0];
#pragma unroll
        for (int rr = 0; rr < 4; ++rr) {
          float av = ELT(A_[rr], u), hv = ELT(H_[rr], u);
          acc[rr].x = fmaf(av, wl.x, fmaf(hv, wr2.x, acc[rr].x));
          acc[rr].y = fmaf(av, wl.y, fmaf(hv, wr2.y, acc[rr].y));
          acc[rr].z = fmaf(av, wl.z, fmaf(hv, wr2.z, acc[rr].z));
          acc[rr].w = fmaf(av, wl.w, fmaf(hv, wr2.w, acc[rr].w));
        }
      }
    }
  }
  float4 b4 = *(const float4*)&bias[j0];
#pragma unroll
  for (int rr = 0; rr < 4; ++rr) {
    int row = row0 + r0 + rr;
    if (row < n) {
      float4 o = acc[rr];
      o.x += b4.x; o.y += b4.y; o.z += b4.z; o.w += b4.w;
      if (do_relu) {
        o.x = fmaxf(o.x, 0.f); o.y = fmaxf(o.y, 0.f);
        o.z = fmaxf(o.z, 0.f); o.w = fmaxf(o.w, 0.f);
      }
      *(float4*)&out[(size_t)row * HID + j0] = o;
    }
  }
}

// ---------------------------------------------------------------- single GEMM: out = h@W + b (no relu)
__global__ __launch_bounds__(256) void k_single(const float* __restrict__ hs,
                                                const float* __restrict__ W,
                                                const float* __restrict__ bias,
                                                float* __restrict__ out, int n) {
  __shared__ float sW[32][HID];
  __shared__ float sH[32][32];
  int tid = threadIdx.x;
  int cg = tid & 31, rg = tid >> 5;
  int j0 = cg << 2, r0 = rg << 2;
  int row0 = blockIdx.x << 5;
  float4 acc[4];
#pragma unroll
  for (int rr = 0; rr < 4; ++rr) acc[rr] = make_float4(0.f, 0.f, 0.f, 0.f);

  for (int kc = 0; kc < HID; kc += 32) {
    __syncthreads();
#pragma unroll
    for (int i = 0; i < 4; ++i) {
      int f = tid + (i << 8);
      int wr_ = f >> 5, wc = (f & 31) << 2;
      *(float4*)&sW[wr_][wc] = *(const float4*)&W[(kc + wr_) * HID + wc];
    }
    {
      int rr_ = tid >> 3, kk = (tid & 7) << 2;
      int row = row0 + rr_;
      float4 vh = make_float4(0.f, 0.f, 0.f, 0.f);
      if (row < n) vh = *(const float4*)&hs[(size_t)row * HID + kc + kk];
      *(float4*)&sH[rr_][kk] = vh;
    }
    __syncthreads();
#pragma unroll
    for (int k = 0; k < 32; k += 4) {
      float4 H_[4];
#pragma unroll
      for (int rr = 0; rr < 4; ++rr) H_[rr] = *(const float4*)&sH[r0 + rr][k];
#pragma unroll
      for (int u = 0; u < 4; ++u) {
        float4 w = *(const float4*)&sW[k + u][j0];
#pragma unroll
        for (int rr = 0; rr < 4; ++rr) {
          float hv = ELT(H_[rr], u);
          acc[rr].x = fmaf(hv, w.x, acc[rr].x);
          acc[rr].y = fmaf(hv, w.y, acc[rr].y);
          acc[rr].z = fmaf(hv, w.z, acc[rr].z);
          acc[rr].w = fmaf(hv, w.w, acc[rr].w);
        }
      }
    }
  }
  float4 b4 = *(const float4*)&bias[j0];
#pragma unroll
  for (int rr = 0; rr < 4; ++rr) {
    int row = row0 + r0 + rr;
    if (row < n) {
      float4 o = acc[rr];
      o.x += b4.x; o.y += b4.y; o.z += b4.z; o.w += b4.w;
      *(float4*)&out[(size_t)row * HID + j0] = o;
    }
  }
}

// ---------------------------------------------------------------- column mean
__global__ __launch_bounds__(256) void k_colmean(const float* __restrict__ ns,
                                                 float* __restrict__ outmean,
                                                 int n, float inv) {
  __shared__ float red[256];
  int t = threadIdx.x;
  int col = t & 127, rp = t >> 7;
  int row0 = blockIdx.x * 256;
  float s = 0.f;
  for (int rr = rp; rr < 256; rr += 2) {
    int row = row0 + rr;
    if (row < n) s += ns[(size_t)row * HID + col];
  }
  red[t] = s;
  __syncthreads();
  if (t < 128) atomicAdd(&outmean[col], (red[t] + red[t + 128]) * inv);
}

// ---------------------------------------------------------------- launch
extern "C" void kernel_launch(void* const* d_in, const int* in_sizes, int n_in,
                              void* d_out, int out_size, void* d_ws, size_t ws_size,
                              hipStream_t stream) {
  const float* pos  = (const float*)d_in[0];
  const int*   an   = (const int*)d_in[1];
  const int*   ei   = (const int*)d_in[2];
  const float* Win  = (const float*)d_in[3];
  const float* bin  = (const float*)d_in[4];
  const float* W1l  = (const float*)d_in[5];
  const float* b1   = (const float*)d_in[6];
  const float* W1r  = (const float*)d_in[7];
  const float* W2l  = (const float*)d_in[8];
  const float* b2   = (const float*)d_in[9];
  const float* W2r  = (const float*)d_in[10];
  const float* Wout = (const float*)d_in[11];
  const float* bout = (const float*)d_in[12];

  int N = in_sizes[0] / 3;
  int E = in_sizes[2] / 2;
  const int* srcl = ei;
  const int* dstl = ei + E;

  float* outmean = (float*)d_out;
  float* ns      = (float*)d_out + HID;

  char* p = (char*)d_ws;
  auto take = [&](size_t bytes) {
    char* q = p;
    p += (bytes + 255) & ~(size_t)255;
    return q;
  };
  float* A       = (float*)take((size_t)N * HID * 4);
  float* B       = (float*)take((size_t)N * HID * 4);
  float* D       = (float*)take((size_t)N * HID * 4);
  int*   cnt     = (int*)take((size_t)N * 4);
  int*   offs    = (int*)take((size_t)(N + 1) * 4);
  int*   cursor  = (int*)take((size_t)N * 4);
  int*   csr     = (int*)take((size_t)E * 4);
  int*   partial = (int*)take((size_t)256 * 4);

  int gN256   = (N + 255) / 256;
  int gE256   = (E + 255) / 256;
  int gEmbed  = (int)(((size_t)N * 32 + 255) / 256);
  int gTile32 = (N + 31) / 32;
  int gWave   = (N + 3) / 4;
  int nbScan  = (N + SCAN_CHUNK - 1) / SCAN_CHUNK;

  k_init<<<gN256, 256, 0, stream>>>(cnt, outmean, N);
  k_embed<<<gEmbed, 256, 0, stream>>>(pos, an, Win, bin, A, N);
  k_count<<<gE256, 256, 0, stream>>>(dstl, cnt, E);
  k_scan_blocksum<<<nbScan, 256, 0, stream>>>(cnt, partial, N);
  k_scan_partials<<<1, 256, 0, stream>>>(partial, nbScan);
  k_scan_write<<<nbScan, 256, 0, stream>>>(cnt, partial, offs, cursor, N, E);
  k_fill<<<gE256, 256, 0, stream>>>(srcl, dstl, cursor, csr, E);

  // conv1
  k_aggmean<<<gWave, 256, 0, stream>>>(A, csr, offs, D, N);
  k_sage<<<gTile32, 256, 0, stream>>>(D, A, W1l, W1r, b1, B, N, 1);
  // conv2
  k_aggmean<<<gWave, 256, 0, stream>>>(B, csr, offs, D, N);
  k_sage<<<gTile32, 256, 0, stream>>>(D, B, W2l, W2r, b2, A, N, 1);
  // output projection
  k_single<<<gTile32, 256, 0, stream>>>(A, Wout, bout, ns, N);
  k_colmean<<<gN256, 256, 0, stream>>>(ns, outmean, N, 1.0f / (float)N);
}